// Round 1
// baseline (308.718 us; speedup 1.0000x reference)
//
#include <hip/hip_runtime.h>

#define SOS_IDX 1
#define EOS_IDX 2
#define B 32
#define T 256
#define K 128

// One block per batch element b. Thread j owns output state j.
// Recurrence run in exp domain: v_t[j] = exp(h[t,j]) * sum_i v_{t-1}[i] * exp(T[i,j])
// with running log-offset c (rescaled when v[0] > 1e20; decision is wave-uniform
// since every thread reads the same v[0]).
__global__ __launch_bounds__(K) void crf_fwd(const float* __restrict__ h,
                                             const float* __restrict__ trans,
                                             const int* __restrict__ lengths,
                                             float* __restrict__ out) {
    const int b = blockIdx.x;
    const int j = threadIdx.x;
    const int len = lengths[b];

    __shared__ float vbuf[2][K];

    // Column j of exp(transition) held in registers: et[i] = exp(T[i][j]).
    // Loads are coalesced across j for each i. Time-invariant -> hoisted out of scan.
    float et[K];
#pragma unroll
    for (int i = 0; i < K; ++i) {
        et[i] = __expf(trans[i * K + j]);
    }

    // alpha0[j] = h[b,0,j] + T[SOS,j]
    float a0 = h[(b * T + 0) * K + j] + trans[SOS_IDX * K + j];
    float vcur = __expf(a0);   // |a0| <~ 10, safe
    float c = 0.0f;
    vbuf[0][j] = vcur;
    __syncthreads();

    int cur = 0;
    for (int t = 1; t < len; ++t) {
        // issue global load for this step early; consumed only after the dot loop
        float hv = h[(b * T + t) * K + j];
        float eh = __expf(hv);

        const float4* vp = (const float4*)vbuf[cur];
        float acc[4] = {0.0f, 0.0f, 0.0f, 0.0f};
        float v0 = 1.0f;
#pragma unroll
        for (int i4 = 0; i4 < K / 4; ++i4) {
            float4 x = vp[i4];                       // broadcast LDS read (same addr all lanes)
            if (i4 == 0) v0 = x.x;
            float p = fmaf(x.x, et[4 * i4 + 0],
                      fmaf(x.y, et[4 * i4 + 1],
                      fmaf(x.z, et[4 * i4 + 2],
                           x.w * et[4 * i4 + 3])));
            acc[i4 & 3] += p;                        // 4 independent chains for ILP
        }
        float s = ((acc[0] + acc[1]) + (acc[2] + acc[3])) * eh;

        // Deterministic uniform rescale: all threads saw identical v0.
        if (v0 > 1e20f) {
            s *= (1.0f / v0);
            c += logf(v0);
        }

        cur ^= 1;
        vbuf[cur][j] = s;
        vcur = s;
        __syncthreads();
    }

    if (j == EOS_IDX) {
        // Z_b = c + log(v[EOS]); loss contribution Z_b / B
        atomicAdd(out, (c + logf(vcur)) * (1.0f / (float)B));
    }
}

// Gold path score: sum over (b, t<len) of h[b,t,y[t]] + T[prev_y, y[t]],
// contributed to the loss with negative sign, / B.
__global__ __launch_bounds__(T) void crf_gold(const float* __restrict__ h,
                                              const float* __restrict__ trans,
                                              const int* __restrict__ y,
                                              const int* __restrict__ lengths,
                                              float* __restrict__ out) {
    const int b = blockIdx.x;
    const int t = threadIdx.x;
    const int len = lengths[b];

    float g = 0.0f;
    if (t < len) {
        int yt = y[b * T + t];
        int prev = (t == 0) ? SOS_IDX : y[b * T + t - 1];
        g = h[(b * T + t) * K + yt] + trans[prev * K + yt];
    }

    // wave (64-lane) shuffle reduce, then cross-wave via LDS
#pragma unroll
    for (int off = 32; off > 0; off >>= 1) {
        g += __shfl_down(g, off);
    }
    __shared__ float ws[T / 64];
    int lane = t & 63, wid = t >> 6;
    if (lane == 0) ws[wid] = g;
    __syncthreads();
    if (t == 0) {
        float tot = 0.0f;
#pragma unroll
        for (int w = 0; w < T / 64; ++w) tot += ws[w];
        atomicAdd(out, -tot * (1.0f / (float)B));
    }
}

extern "C" void kernel_launch(void* const* d_in, const int* in_sizes, int n_in,
                              void* d_out, int out_size, void* d_ws, size_t ws_size,
                              hipStream_t stream) {
    const float* h       = (const float*)d_in[0];
    const float* trans   = (const float*)d_in[1];
    const int*   y       = (const int*)d_in[2];
    const int*   lengths = (const int*)d_in[3];
    // d_in[4] = mask: ignored, derived from lengths instead.
    float* out = (float*)d_out;

    hipMemsetAsync(out, 0, sizeof(float), stream);
    crf_gold<<<B, T, 0, stream>>>(h, trans, y, lengths, out);
    crf_fwd<<<B, K, 0, stream>>>(h, trans, lengths, out);
}

// Round 2
// 233.054 us; speedup vs baseline: 1.3247x; 1.3247x over previous
//
#include <hip/hip_runtime.h>

#define SOS_IDX 1
#define EOS_IDX 2
#define B 32
#define T 256
#define K 128

// One block per batch element. Thread j owns output state j.
// Exp-domain recurrence: v_t[j] = exp(h[t,j]) * sum_i v_{t-1}[i] * exp(T[i,j]),
// running log-offset c, uniform rescale when v[0] > 1e20 (all threads read the
// same v[0], so the branch is wave-uniform and deterministic).
//
// __launch_bounds__(K, 1): min 1 wave/EU -> VGPR budget ~512/wave, so et[128]
// stays in registers. Round-1 evidence: without this, VGPR_Count=80 => et
// spilled to scratch, ~2350 cyc/step instead of ~600.
__global__ __launch_bounds__(K, 1) void crf_fused(const float* __restrict__ h,
                                                  const float* __restrict__ trans,
                                                  const int* __restrict__ y,
                                                  const int* __restrict__ lengths,
                                                  float* __restrict__ out) {
    const int b = blockIdx.x;
    const int j = threadIdx.x;
    const int len = lengths[b];

    __shared__ float vbuf[2][K];
    __shared__ float gred[2];

    // ---- gold path score, fused (each thread covers t=j and t=j+K) ----
    float g = 0.0f;
    {
        const int t0 = j;
        if (t0 < len) {
            int yt   = y[b * T + t0];
            int prev = (t0 == 0) ? SOS_IDX : y[b * T + t0 - 1];
            g += h[(b * T + t0) * K + yt] + trans[prev * K + yt];
        }
        const int t1 = j + K;
        if (t1 < len) {
            int yt   = y[b * T + t1];
            int prev = y[b * T + t1 - 1];
            g += h[(b * T + t1) * K + yt] + trans[prev * K + yt];
        }
    }
#pragma unroll
    for (int off = 32; off > 0; off >>= 1) g += __shfl_down(g, off);
    if ((j & 63) == 0) gred[j >> 6] = g;

    // ---- column j of exp(transition) in registers (time-invariant) ----
    float et[K];
#pragma unroll
    for (int i = 0; i < K; ++i) et[i] = __expf(trans[i * K + j]);

    // alpha0
    float a0   = h[(b * T) * K + j] + trans[SOS_IDX * K + j];
    float vcur = __expf(a0);
    float c    = 0.0f;
    vbuf[0][j] = vcur;
    __syncthreads();

    if (j == 0) {
        atomicAdd(out, -(gred[0] + gred[1]) * (1.0f / (float)B));
    }

    // 2-deep prefetch pipeline for h rows (hides ~900-cyc HBM miss latency
    // behind >= 2 steps of dot-product work).
    float hv1 = h[(b * T + 1) * K + j];
    float hv2 = h[(b * T + 2) * K + j];

    int cur = 0;
    for (int t = 1; t < len; ++t) {
        float hv = hv1;
        hv1 = hv2;
        int tn = t + 2; if (tn >= T) tn = T - 1;
        hv2 = h[(b * T + tn) * K + j];

        float eh = __expf(hv);

        const float4* vp = (const float4*)vbuf[cur];
        float acc[4] = {0.0f, 0.0f, 0.0f, 0.0f};
        float v0 = 1.0f;
#pragma unroll
        for (int i4 = 0; i4 < K / 4; ++i4) {
            float4 x = vp[i4];                      // broadcast LDS read
            if (i4 == 0) v0 = x.x;
            float p = fmaf(x.x, et[4 * i4 + 0],
                      fmaf(x.y, et[4 * i4 + 1],
                      fmaf(x.z, et[4 * i4 + 2],
                           x.w * et[4 * i4 + 3])));
            acc[i4 & 3] += p;                       // 4 independent chains
        }
        float s = ((acc[0] + acc[1]) + (acc[2] + acc[3])) * eh;

        if (v0 > 1e20f) {                           // wave-uniform rescale
            s *= (1.0f / v0);
            c += logf(v0);
        }

        cur ^= 1;
        vbuf[cur][j] = s;
        vcur = s;
        __syncthreads();
    }

    if (j == EOS_IDX) {
        atomicAdd(out, (c + logf(vcur)) * (1.0f / (float)B));
    }
}

extern "C" void kernel_launch(void* const* d_in, const int* in_sizes, int n_in,
                              void* d_out, int out_size, void* d_ws, size_t ws_size,
                              hipStream_t stream) {
    const float* h       = (const float*)d_in[0];
    const float* trans   = (const float*)d_in[1];
    const int*   y       = (const int*)d_in[2];
    const int*   lengths = (const int*)d_in[3];
    // d_in[4] = mask: derived from lengths instead.
    float* out = (float*)d_out;

    hipMemsetAsync(out, 0, sizeof(float), stream);
    crf_fused<<<B, K, 0, stream>>>(h, trans, y, lengths, out);
}

// Round 3
// 185.015 us; speedup vs baseline: 1.6686x; 1.2597x over previous
//
#include <hip/hip_runtime.h>

#define SOS_IDX 1
#define EOS_IDX 2
#define B 32
#define T 256
#define K 128
#define HALF_K 64

// One block per batch element, 256 threads = 4 waves.
// Thread pair (2j, 2j+1) owns state j: lane half = tid&1 dots v[half*64 .. +64)
// against its half of column j of exp(transition) (64 registers/lane -> no
// spill; round-2 evidence: a 128-reg et column gets spilled at VGPR_Count=124
// regardless of launch bounds). Pair combine via __shfl_xor(1) within-wave.
//
// Exp-domain recurrence: v_t[j] = exp(h[t,j]) * sum_i v_{t-1}[i]*exp(T[i,j]),
// running log-offset c, wave-uniform rescale when v[0] > 1e20.
__global__ __launch_bounds__(2 * K, 1) void crf_fused(const float* __restrict__ h,
                                                      const float* __restrict__ trans,
                                                      const int* __restrict__ y,
                                                      const int* __restrict__ lengths,
                                                      float* __restrict__ out) {
    const int b    = blockIdx.x;
    const int tid  = threadIdx.x;
    const int j    = tid >> 1;    // state owned by this lane pair
    const int half = tid & 1;     // which half of the i-range this lane dots
    const int len  = lengths[b];

    __shared__ float vbuf[2][K];
    __shared__ float gred[4];

    // ---- gold path score, fused (t = tid, covers all T=256) ----
    float g = 0.0f;
    if (tid < len) {
        int yt   = y[b * T + tid];
        int prev = (tid == 0) ? SOS_IDX : y[b * T + tid - 1];
        g = h[(b * T + tid) * K + yt] + trans[prev * K + yt];
    }
#pragma unroll
    for (int off = 32; off > 0; off >>= 1) g += __shfl_down(g, off);
    if ((tid & 63) == 0) gred[tid >> 6] = g;

    // ---- half-column of exp(transition) in registers (time-invariant) ----
    float et[HALF_K];
#pragma unroll
    for (int i = 0; i < HALF_K; ++i) {
        et[i] = __expf(trans[(half * HALF_K + i) * K + j]);
    }

    // alpha0 (both lanes of a pair compute identically)
    float a0   = h[(b * T) * K + j] + trans[SOS_IDX * K + j];
    float vcur = __expf(a0);
    float c    = 0.0f;
    if (half == 0) vbuf[0][j] = vcur;
    __syncthreads();

    if (tid == 0) {
        atomicAdd(out, -(gred[0] + gred[1] + gred[2] + gred[3]) * (1.0f / (float)B));
    }

    // 2-deep prefetch pipeline for h (hides HBM/L2 latency behind 2 steps)
    float hv1 = h[(b * T + 1) * K + j];
    float hv2 = h[(b * T + 2) * K + j];

    int cur = 0;
    for (int t = 1; t < len; ++t) {
        float hv = hv1;
        hv1 = hv2;
        int tn = t + 2; if (tn >= T) tn = T - 1;
        hv2 = h[(b * T + tn) * K + j];

        float v0 = vbuf[cur][0];                    // uniform: rescale trigger
        const float4* vp = (const float4*)&vbuf[cur][half * HALF_K];
        float acc[4] = {0.0f, 0.0f, 0.0f, 0.0f};
#pragma unroll
        for (int i4 = 0; i4 < HALF_K / 4; ++i4) {
            float4 x = vp[i4];                      // near-broadcast LDS read (2 uniq addrs)
            float p = fmaf(x.x, et[4 * i4 + 0],
                      fmaf(x.y, et[4 * i4 + 1],
                      fmaf(x.z, et[4 * i4 + 2],
                           x.w * et[4 * i4 + 3])));
            acc[i4 & 3] += p;                       // 4 independent chains
        }
        float sp = (acc[0] + acc[1]) + (acc[2] + acc[3]);
        float s  = (sp + __shfl_xor(sp, 1)) * __expf(hv);  // pair combine + eh

        if (v0 > 1e20f) {                           // wave-uniform rescale
            s *= (1.0f / v0);
            c += logf(v0);
        }

        cur ^= 1;
        if (half == 0) vbuf[cur][j] = s;
        vcur = s;
        __syncthreads();
    }

    if (j == EOS_IDX && half == 0) {
        atomicAdd(out, (c + logf(vcur)) * (1.0f / (float)B));
    }
}

extern "C" void kernel_launch(void* const* d_in, const int* in_sizes, int n_in,
                              void* d_out, int out_size, void* d_ws, size_t ws_size,
                              hipStream_t stream) {
    const float* h       = (const float*)d_in[0];
    const float* trans   = (const float*)d_in[1];
    const int*   y       = (const int*)d_in[2];
    const int*   lengths = (const int*)d_in[3];
    // d_in[4] = mask: derived from lengths instead.
    float* out = (float*)d_out;

    hipMemsetAsync(out, 0, sizeof(float), stream);
    crf_fused<<<B, 2 * K, 0, stream>>>(h, trans, y, lengths, out);
}